// Round 4
// baseline (284.906 us; speedup 1.0000x reference)
//
#include <hip/hip_runtime.h>

// CognitiveLorenzField: 500-step scan over DIM=65536 vectors.
// Exact 2D-subspace reduction: vL_t = p_t*vL0, vJ_t = q_t*vL0 + r_t*vJ0.
//
// R6 -> R7: single fused kernel. Blocks 0..63 compute the two dot-product
// partials and publish them via __threadfence + device-scope atomicAdd on a
// flag (zeroed each replay by a graph-captured hipMemsetAsync; ws may be
// poisoned). All 800 blocks issue their register-cached slice loads first
// (hidden under the spin), wave 0 spin-acquires the flag, reduces partials
// in the same shuffle order (bit-identical), runs the recurrence prologue.
// tg-mapping reversed so the longest prologues start first; store phases
// split (all outL rows, then all outJ rows) for single-stream locality.
// Deadlock-safe: all 800 blocks co-resident (4 blocks/CU fits waves/VGPR/
// LDS budgets), producers dispatched first.

#define DIM 65536
#define STEPS 500
#define DIM4 (DIM / 4)            // 16384 float4 per vector per step
#define T_GRP 10                  // time steps per block
#define NTG (STEPS / T_GRP)       // 50 t-groups
#define JBLK 16                   // j-slices per step-row
#define SLICE_F4 1024             // float4 per j-slice (4 per thread per vector)
#define NBLK (NTG * JBLK)         // 800 blocks, all co-resident

typedef float vfloat4 __attribute__((ext_vector_type(4)));

__device__ constexpr float ALPHA0 = 1.0f;
__device__ constexpr float BETA_GAME = 0.2f;
__device__ constexpr float GAMMA_C = 0.5f;
__device__ constexpr float SIGMA = 10.0f;
__device__ constexpr float RHO = 28.0f;
__device__ constexpr float LORENZ_BETA = 8.0f / 3.0f;
__device__ constexpr float DT = 0.01f;
__device__ constexpr float EPS = 1e-8f;

// ws layout (floats):
//   [0..63]    per-block partial of vL0.vL0
//   [64..127]  per-block partial of vL0.vJ0
//   [128]      producer-done flag (uint32), memset to 0 before each launch

__global__ __launch_bounds__(256) void fused_all(const vfloat4* __restrict__ vL,
                                                 const vfloat4* __restrict__ vJ,
                                                 float* __restrict__ ws,
                                                 vfloat4* __restrict__ outL,
                                                 vfloat4* __restrict__ outJ,
                                                 float* __restrict__ outZ) {
    __shared__ float pb[T_GRP], qb[T_GRP], rb[T_GRP];
    __shared__ __align__(16) float zbuf[STEPS];

    const int  b   = blockIdx.x;
    const int  tid = threadIdx.x;
    const int  tg  = (NTG - 1) - (b >> 4);    // reversed: longest prologue first
    const int  jb  = b & (JBLK - 1);
    const int  t0  = tg * T_GRP;
    const bool zW  = (b == 0);                // tg=49, jb=0: passes all 500 steps

    unsigned* flag = (unsigned*)(ws + 128);

    // ---- producer phase: blocks 0..63 compute dot partials for chunk b ----
    if (b < 64) {
        vfloat4 a = vL[b * 256 + tid];        // identical indexing to old
        vfloat4 v = vJ[b * 256 + tid];        // dot_partials -> same bits
        float sL  = a.x * a.x + a.y * a.y + a.z * a.z + a.w * a.w;
        float sLJ = a.x * v.x + a.y * v.y + a.z * v.z + a.w * v.w;
        #pragma unroll
        for (int off = 32; off > 0; off >>= 1) {
            sL  += __shfl_down(sL,  off, 64);
            sLJ += __shfl_down(sLJ, off, 64);
        }
        __shared__ float redL[4], redLJ[4];
        int wave = tid >> 6;
        if ((tid & 63) == 0) { redL[wave] = sL; redLJ[wave] = sLJ; }
        __syncthreads();
        if (tid == 0) {
            ws[b]      = redL[0] + redL[1] + redL[2] + redL[3];
            ws[64 + b] = redLJ[0] + redLJ[1] + redLJ[2] + redLJ[3];
            __threadfence();                  // release partials...
            atomicAdd(flag, 1u);              // ...then publish (device scope)
        }
    }

    // ---- issue register-cache slice loads early (hidden under the spin) ----
    const int jbase = jb * SLICE_F4;
    vfloat4 aL[4], aJ[4];
    #pragma unroll
    for (int k = 0; k < 4; ++k) {
        aL[k] = vL[jbase + k * 256 + tid];
        aJ[k] = vJ[jbase + k * 256 + tid];
    }

    // ---- wave 0: acquire partials, reduce, run recurrence ----
    if (tid < 64) {
        while (__hip_atomic_load(flag, __ATOMIC_ACQUIRE,
                                 __HIP_MEMORY_SCOPE_AGENT) != 64u)
            __builtin_amdgcn_s_sleep(8);

        float sL  = ws[tid];
        float sLJ = ws[64 + tid];
        #pragma unroll
        for (int off = 32; off > 0; off >>= 1) {
            sL  += __shfl_down(sL,  off, 64);
            sLJ += __shfl_down(sLJ, off, 64);
        }
        const float L00 = __shfl(sL, 0, 64);
        const float L01 = __shfl(sLJ, 0, 64);

        float x = 1.f, y = 1.f, z = 1.f;
        float p = 1.f, q = 0.f, r = 1.f;
        for (int t = 0; t < t0; ++t) {        // prologue: steps [0, t0)
            float dx = SIGMA * (y - x);
            float dy = x * (RHO - z) - y;
            float dz = x * y - LORENZ_BETA * z;
            x += DT * dx;
            y += DT * dy;
            z += DT * dz;
            float alpha = ALPHA0 + GAMMA_C * z;
            float dot = p * (q * L00 + r * L01);
            float nsq = p * p * L00 + EPS;
            float c   = dot * __builtin_amdgcn_rcpf(nsq);
            float pn = p * (1.0f + DT * (alpha * (c - 1.0f) + BETA_GAME));
            float decay = 1.0f - DT * (alpha + BETA_GAME);
            float qn = q * decay + DT * p * (alpha * c + BETA_GAME);
            float rn = r * decay;
            p = pn; q = qn; r = rn;
            if (zW && tid == 0) zbuf[t] = z;
        }
        for (int tt = 0; tt < T_GRP; ++tt) {  // main: steps [t0, t0+10)
            float dx = SIGMA * (y - x);
            float dy = x * (RHO - z) - y;
            float dz = x * y - LORENZ_BETA * z;
            x += DT * dx;
            y += DT * dy;
            z += DT * dz;
            float alpha = ALPHA0 + GAMMA_C * z;
            float dot = p * (q * L00 + r * L01);
            float nsq = p * p * L00 + EPS;
            float c   = dot * __builtin_amdgcn_rcpf(nsq);
            float pn = p * (1.0f + DT * (alpha * (c - 1.0f) + BETA_GAME));
            float decay = 1.0f - DT * (alpha + BETA_GAME);
            float qn = q * decay + DT * p * (alpha * c + BETA_GAME);
            float rn = r * decay;
            p = pn; q = qn; r = rn;
            if (tid == 0) {
                pb[tt] = p; qb[tt] = q; rb[tt] = r;
                if (zW) zbuf[t0 + tt] = z;
            }
        }
    }
    __syncthreads();

    if (zW) {                                 // bulk-write z trajectory
        if (tid < STEPS / 4)
            ((vfloat4*)outZ)[tid] = ((const vfloat4*)zbuf)[tid];
    }

    // ---- pure store streams: outL rows first, then outJ rows ----
    const long base = (long)t0 * DIM4 + jbase;
    for (int tt = 0; tt < T_GRP; ++tt) {
        const float p = pb[tt];
        #pragma unroll
        for (int k = 0; k < 4; ++k)
            outL[base + (long)tt * DIM4 + k * 256 + tid] = p * aL[k];
    }
    for (int tt = 0; tt < T_GRP; ++tt) {
        const float q = qb[tt], r = rb[tt];
        #pragma unroll
        for (int k = 0; k < 4; ++k)
            outJ[base + (long)tt * DIM4 + k * 256 + tid] = q * aL[k] + r * aJ[k];
    }
}

extern "C" void kernel_launch(void* const* d_in, const int* in_sizes, int n_in,
                              void* d_out, int out_size, void* d_ws, size_t ws_size,
                              hipStream_t stream) {
    const vfloat4* vL = (const vfloat4*)d_in[0];
    const vfloat4* vJ = (const vfloat4*)d_in[1];
    float* out = (float*)d_out;
    float* ws  = (float*)d_ws;

    float* outL = out;                                   // [500 * 65536]
    float* outJ = out + (size_t)STEPS * DIM;             // [500 * 65536]
    float* outZ = out + 2ull * STEPS * DIM;              // [500]

    // Zero the producer flag (ws may be poisoned); graph-capturable.
    hipMemsetAsync(ws + 128, 0, sizeof(unsigned), stream);
    fused_all<<<NBLK, 256, 0, stream>>>(vL, vJ, ws,
                                        (vfloat4*)outL, (vfloat4*)outJ, outZ);
}

// Round 5
// 273.769 us; speedup vs baseline: 1.0407x; 1.0407x over previous
//
#include <hip/hip_runtime.h>

// CognitiveLorenzField: 500-step scan over DIM=65536 vectors.
// Exact 2D-subspace reduction: vL_t = p_t*vL0, vJ_t = q_t*vL0 + r_t*vJ0.
//
// R7 -> R8: revert the fused/spin experiment (regressed +20 us). Back to the
// R6 structure (best: 264.75 us), single change: outL/outJ stores are
// NONTEMPORAL (bypass L2 allocate). Theory: plain streaming stores churn the
// 32 MB L2 via write-allocate + lazy writeback (~2.7 TB/s observed); the
// 6.6 TB/s rocclr fill uses streaming stores. nt frees the write path.
// All float ops identical -> bitwise-identical outputs.

#define DIM 65536
#define STEPS 500
#define DIM4 (DIM / 4)            // 16384 float4 per vector per step
#define T_GRP 10                  // time steps per block
#define NTG (STEPS / T_GRP)       // 50 t-groups
#define JBLK 16                   // j-slices per step-row
#define SLICE_F4 1024             // float4 per j-slice (4 per thread per vector)
#define NBLK (NTG * JBLK)         // 800 blocks, all co-resident

typedef float vfloat4 __attribute__((ext_vector_type(4)));

__device__ constexpr float ALPHA0 = 1.0f;
__device__ constexpr float BETA_GAME = 0.2f;
__device__ constexpr float GAMMA_C = 0.5f;
__device__ constexpr float SIGMA = 10.0f;
__device__ constexpr float RHO = 28.0f;
__device__ constexpr float LORENZ_BETA = 8.0f / 3.0f;
__device__ constexpr float DT = 0.01f;
__device__ constexpr float EPS = 1e-8f;

// ws layout (floats):
//   [0..63]      per-block partial of vL0.vL0
//   [64..127]    per-block partial of vL0.vJ0

__global__ __launch_bounds__(256) void dot_partials(const vfloat4* __restrict__ vL,
                                                    const vfloat4* __restrict__ vJ,
                                                    float* __restrict__ ws) {
    int tid = threadIdx.x;
    int idx = blockIdx.x * 256 + tid;          // 64 blocks * 256 = 16384 = DIM4
    vfloat4 a = vL[idx];
    vfloat4 b = vJ[idx];
    float sL  = a.x * a.x + a.y * a.y + a.z * a.z + a.w * a.w;
    float sLJ = a.x * b.x + a.y * b.y + a.z * b.z + a.w * b.w;
    #pragma unroll
    for (int off = 32; off > 0; off >>= 1) {
        sL  += __shfl_down(sL,  off, 64);
        sLJ += __shfl_down(sLJ, off, 64);
    }
    __shared__ float redL[4], redLJ[4];
    int wave = tid >> 6;
    if ((tid & 63) == 0) { redL[wave] = sL; redLJ[wave] = sLJ; }
    __syncthreads();
    if (tid == 0) {
        ws[blockIdx.x]      = redL[0] + redL[1] + redL[2] + redL[3];
        ws[64 + blockIdx.x] = redLJ[0] + redLJ[1] + redLJ[2] + redLJ[3];
    }
}

// 800 blocks: b = tg*16 + jb. Block owns j-slice [jb*1024, jb*1024+1024) of
// the 16384-f4 step-row, for 10 consecutive steps t in [tg*10, tg*10+10).
__global__ __launch_bounds__(256) void expand_fused(const vfloat4* __restrict__ vL,
                                                    const vfloat4* __restrict__ vJ,
                                                    const float* __restrict__ ws,
                                                    vfloat4* __restrict__ outL,
                                                    vfloat4* __restrict__ outJ,
                                                    float* __restrict__ outZ) {
    __shared__ float pb[T_GRP], qb[T_GRP], rb[T_GRP];
    __shared__ __align__(16) float zbuf[STEPS];

    const int  b   = blockIdx.x;
    const int  jb  = b & (JBLK - 1);
    const int  tg  = b >> 4;
    const int  t0  = tg * T_GRP;
    const int  tid = threadIdx.x;
    const bool zW  = (tg == NTG - 1) && (jb == 0);   // passes through all 500 z

    // Issue the slice loads first; latency hides under the recurrence.
    const int jbase = jb * SLICE_F4;
    vfloat4 aL[4], aJ[4];
    #pragma unroll
    for (int k = 0; k < 4; ++k) {
        aL[k] = vL[jbase + k * 256 + tid];
        aJ[k] = vJ[jbase + k * 256 + tid];
    }

    if (tid < 64) {                           // wave 0 only: recurrence
        // Deterministic 64->1 reduction (same order as before -> same bits).
        float sL  = ws[tid];
        float sLJ = ws[64 + tid];
        #pragma unroll
        for (int off = 32; off > 0; off >>= 1) {
            sL  += __shfl_down(sL,  off, 64);
            sLJ += __shfl_down(sLJ, off, 64);
        }
        const float L00 = __shfl(sL, 0, 64);
        const float L01 = __shfl(sLJ, 0, 64);

        float x = 1.f, y = 1.f, z = 1.f;
        float p = 1.f, q = 0.f, r = 1.f;
        // Prologue: steps [0, t0)
        for (int t = 0; t < t0; ++t) {
            float dx = SIGMA * (y - x);
            float dy = x * (RHO - z) - y;
            float dz = x * y - LORENZ_BETA * z;
            x += DT * dx;
            y += DT * dy;
            z += DT * dz;
            float alpha = ALPHA0 + GAMMA_C * z;
            float dot = p * (q * L00 + r * L01);
            float nsq = p * p * L00 + EPS;
            float c   = dot * __builtin_amdgcn_rcpf(nsq);
            float pn = p * (1.0f + DT * (alpha * (c - 1.0f) + BETA_GAME));
            float decay = 1.0f - DT * (alpha + BETA_GAME);
            float qn = q * decay + DT * p * (alpha * c + BETA_GAME);
            float rn = r * decay;
            p = pn; q = qn; r = rn;
            if (zW && tid == 0) zbuf[t] = z;
        }
        // Main: steps [t0, t0+T_GRP), stage coefficients in LDS.
        for (int tt = 0; tt < T_GRP; ++tt) {
            float dx = SIGMA * (y - x);
            float dy = x * (RHO - z) - y;
            float dz = x * y - LORENZ_BETA * z;
            x += DT * dx;
            y += DT * dy;
            z += DT * dz;
            float alpha = ALPHA0 + GAMMA_C * z;
            float dot = p * (q * L00 + r * L01);
            float nsq = p * p * L00 + EPS;
            float c   = dot * __builtin_amdgcn_rcpf(nsq);
            float pn = p * (1.0f + DT * (alpha * (c - 1.0f) + BETA_GAME));
            float decay = 1.0f - DT * (alpha + BETA_GAME);
            float qn = q * decay + DT * p * (alpha * c + BETA_GAME);
            float rn = r * decay;
            p = pn; q = qn; r = rn;
            if (tid == 0) {
                pb[tt] = p; qb[tt] = q; rb[tt] = r;
                if (zW) zbuf[t0 + tt] = z;
            }
        }
    }
    __syncthreads();

    if (zW) {                                 // bulk-write z trajectory
        if (tid < STEPS / 4)
            ((vfloat4*)outZ)[tid] = ((const vfloat4*)zbuf)[tid];
    }

    // Pure store stream: 80 nontemporal dwordx4 stores per thread.
    long base = (long)t0 * DIM4 + jbase;      // flat f4 index of (t0, jbase)
    for (int tt = 0; tt < T_GRP; ++tt) {
        const float p = pb[tt], q = qb[tt], r = rb[tt];
        #pragma unroll
        for (int k = 0; k < 4; ++k) {
            long f = base + k * 256 + tid;
            __builtin_nontemporal_store(p * aL[k], &outL[f]);
            __builtin_nontemporal_store(q * aL[k] + r * aJ[k], &outJ[f]);
        }
        base += DIM4;
    }
}

extern "C" void kernel_launch(void* const* d_in, const int* in_sizes, int n_in,
                              void* d_out, int out_size, void* d_ws, size_t ws_size,
                              hipStream_t stream) {
    const vfloat4* vL = (const vfloat4*)d_in[0];
    const vfloat4* vJ = (const vfloat4*)d_in[1];
    float* out = (float*)d_out;
    float* ws  = (float*)d_ws;

    float* outL = out;                                   // [500 * 65536]
    float* outJ = out + (size_t)STEPS * DIM;             // [500 * 65536]
    float* outZ = out + 2ull * STEPS * DIM;              // [500]

    dot_partials<<<64, 256, 0, stream>>>(vL, vJ, ws);
    expand_fused<<<NBLK, 256, 0, stream>>>(vL, vJ, ws,
                                           (vfloat4*)outL, (vfloat4*)outJ, outZ);
}

// Round 6
// 264.814 us; speedup vs baseline: 1.0759x; 1.0338x over previous
//
#include <hip/hip_runtime.h>

// CognitiveLorenzField: 500-step scan over DIM=65536 vectors.
// Exact 2D-subspace reduction: vL_t = p_t*vL0, vJ_t = q_t*vL0 + r_t*vJ0.
//
// R8 -> R9: nt stores were neutral (R8's +9 us tracks its 5%-slower fills)
// -> revert to plain stores (R6 exact). Single change vs R6: T_GRP 10->20
// (NBLK 800->400). Halves the redundant serial recurrence work
// (sum-of-prologues 196k -> 96k wave-iterations) and its VALU issue
// contention with the store stream; ~6 waves/CU still saturates store BW.
// Float-op sequence unchanged -> bitwise-identical outputs.

#define DIM 65536
#define STEPS 500
#define DIM4 (DIM / 4)            // 16384 float4 per vector per step
#define T_GRP 20                  // time steps per block
#define NTG (STEPS / T_GRP)       // 25 t-groups
#define JBLK 16                   // j-slices per step-row
#define SLICE_F4 1024             // float4 per j-slice (4 per thread per vector)
#define NBLK (NTG * JBLK)         // 400 blocks, all co-resident

typedef float vfloat4 __attribute__((ext_vector_type(4)));

__device__ constexpr float ALPHA0 = 1.0f;
__device__ constexpr float BETA_GAME = 0.2f;
__device__ constexpr float GAMMA_C = 0.5f;
__device__ constexpr float SIGMA = 10.0f;
__device__ constexpr float RHO = 28.0f;
__device__ constexpr float LORENZ_BETA = 8.0f / 3.0f;
__device__ constexpr float DT = 0.01f;
__device__ constexpr float EPS = 1e-8f;

// ws layout (floats):
//   [0..63]      per-block partial of vL0.vL0
//   [64..127]    per-block partial of vL0.vJ0

__global__ __launch_bounds__(256) void dot_partials(const vfloat4* __restrict__ vL,
                                                    const vfloat4* __restrict__ vJ,
                                                    float* __restrict__ ws) {
    int tid = threadIdx.x;
    int idx = blockIdx.x * 256 + tid;          // 64 blocks * 256 = 16384 = DIM4
    vfloat4 a = vL[idx];
    vfloat4 b = vJ[idx];
    float sL  = a.x * a.x + a.y * a.y + a.z * a.z + a.w * a.w;
    float sLJ = a.x * b.x + a.y * b.y + a.z * b.z + a.w * b.w;
    #pragma unroll
    for (int off = 32; off > 0; off >>= 1) {
        sL  += __shfl_down(sL,  off, 64);
        sLJ += __shfl_down(sLJ, off, 64);
    }
    __shared__ float redL[4], redLJ[4];
    int wave = tid >> 6;
    if ((tid & 63) == 0) { redL[wave] = sL; redLJ[wave] = sLJ; }
    __syncthreads();
    if (tid == 0) {
        ws[blockIdx.x]      = redL[0] + redL[1] + redL[2] + redL[3];
        ws[64 + blockIdx.x] = redLJ[0] + redLJ[1] + redLJ[2] + redLJ[3];
    }
}

// 400 blocks: b = tg*16 + jb. Block owns j-slice [jb*1024, jb*1024+1024) of
// the 16384-f4 step-row, for 20 consecutive steps t in [tg*20, tg*20+20).
__global__ __launch_bounds__(256) void expand_fused(const vfloat4* __restrict__ vL,
                                                    const vfloat4* __restrict__ vJ,
                                                    const float* __restrict__ ws,
                                                    vfloat4* __restrict__ outL,
                                                    vfloat4* __restrict__ outJ,
                                                    float* __restrict__ outZ) {
    __shared__ float pb[T_GRP], qb[T_GRP], rb[T_GRP];
    __shared__ __align__(16) float zbuf[STEPS];

    const int  b   = blockIdx.x;
    const int  jb  = b & (JBLK - 1);
    const int  tg  = b >> 4;
    const int  t0  = tg * T_GRP;
    const int  tid = threadIdx.x;
    const bool zW  = (tg == NTG - 1) && (jb == 0);   // passes through all 500 z

    // Issue the slice loads first; latency hides under the recurrence.
    const int jbase = jb * SLICE_F4;
    vfloat4 aL[4], aJ[4];
    #pragma unroll
    for (int k = 0; k < 4; ++k) {
        aL[k] = vL[jbase + k * 256 + tid];
        aJ[k] = vJ[jbase + k * 256 + tid];
    }

    if (tid < 64) {                           // wave 0 only: recurrence
        // Deterministic 64->1 reduction (same order as before -> same bits).
        float sL  = ws[tid];
        float sLJ = ws[64 + tid];
        #pragma unroll
        for (int off = 32; off > 0; off >>= 1) {
            sL  += __shfl_down(sL,  off, 64);
            sLJ += __shfl_down(sLJ, off, 64);
        }
        const float L00 = __shfl(sL, 0, 64);
        const float L01 = __shfl(sLJ, 0, 64);

        float x = 1.f, y = 1.f, z = 1.f;
        float p = 1.f, q = 0.f, r = 1.f;
        // Prologue: steps [0, t0)
        for (int t = 0; t < t0; ++t) {
            float dx = SIGMA * (y - x);
            float dy = x * (RHO - z) - y;
            float dz = x * y - LORENZ_BETA * z;
            x += DT * dx;
            y += DT * dy;
            z += DT * dz;
            float alpha = ALPHA0 + GAMMA_C * z;
            float dot = p * (q * L00 + r * L01);
            float nsq = p * p * L00 + EPS;
            float c   = dot * __builtin_amdgcn_rcpf(nsq);
            float pn = p * (1.0f + DT * (alpha * (c - 1.0f) + BETA_GAME));
            float decay = 1.0f - DT * (alpha + BETA_GAME);
            float qn = q * decay + DT * p * (alpha * c + BETA_GAME);
            float rn = r * decay;
            p = pn; q = qn; r = rn;
            if (zW && tid == 0) zbuf[t] = z;
        }
        // Main: steps [t0, t0+T_GRP), stage coefficients in LDS.
        for (int tt = 0; tt < T_GRP; ++tt) {
            float dx = SIGMA * (y - x);
            float dy = x * (RHO - z) - y;
            float dz = x * y - LORENZ_BETA * z;
            x += DT * dx;
            y += DT * dy;
            z += DT * dz;
            float alpha = ALPHA0 + GAMMA_C * z;
            float dot = p * (q * L00 + r * L01);
            float nsq = p * p * L00 + EPS;
            float c   = dot * __builtin_amdgcn_rcpf(nsq);
            float pn = p * (1.0f + DT * (alpha * (c - 1.0f) + BETA_GAME));
            float decay = 1.0f - DT * (alpha + BETA_GAME);
            float qn = q * decay + DT * p * (alpha * c + BETA_GAME);
            float rn = r * decay;
            p = pn; q = qn; r = rn;
            if (tid == 0) {
                pb[tt] = p; qb[tt] = q; rb[tt] = r;
                if (zW) zbuf[t0 + tt] = z;
            }
        }
    }
    __syncthreads();

    if (zW) {                                 // bulk-write z trajectory
        if (tid < STEPS / 4)
            ((vfloat4*)outZ)[tid] = ((const vfloat4*)zbuf)[tid];
    }

    // Pure store stream: 160 dwordx4 stores per thread, no load dependencies.
    long base = (long)t0 * DIM4 + jbase;      // flat f4 index of (t0, jbase)
    for (int tt = 0; tt < T_GRP; ++tt) {
        const float p = pb[tt], q = qb[tt], r = rb[tt];
        #pragma unroll
        for (int k = 0; k < 4; ++k) {
            long f = base + k * 256 + tid;
            outL[f] = p * aL[k];
            outJ[f] = q * aL[k] + r * aJ[k];
        }
        base += DIM4;
    }
}

extern "C" void kernel_launch(void* const* d_in, const int* in_sizes, int n_in,
                              void* d_out, int out_size, void* d_ws, size_t ws_size,
                              hipStream_t stream) {
    const vfloat4* vL = (const vfloat4*)d_in[0];
    const vfloat4* vJ = (const vfloat4*)d_in[1];
    float* out = (float*)d_out;
    float* ws  = (float*)d_ws;

    float* outL = out;                                   // [500 * 65536]
    float* outJ = out + (size_t)STEPS * DIM;             // [500 * 65536]
    float* outZ = out + 2ull * STEPS * DIM;              // [500]

    dot_partials<<<64, 256, 0, stream>>>(vL, vJ, ws);
    expand_fused<<<NBLK, 256, 0, stream>>>(vL, vJ, ws,
                                           (vfloat4*)outL, (vfloat4*)outJ, outZ);
}